// Round 15
// baseline (147.725 us; speedup 1.0000x reference)
//
#include <hip/hip_runtime.h>
#include <hip/hip_bf16.h>

#define HH 96
#define WW 96
#define HW 9216
#define NB 8

typedef __bf16 bf16x8 __attribute__((ext_vector_type(8)));
typedef float  f32x4  __attribute__((ext_vector_type(4)));

union BF8 { uint4 u; bf16x8 v; unsigned short s[8]; };

__device__ __forceinline__ unsigned short f2bf_bits(float f) {
    unsigned u = __float_as_uint(f);
    unsigned r = u + 0x7FFFu + ((u >> 16) & 1u);     // RNE
    return (unsigned short)(r >> 16);
}
__device__ __forceinline__ float bf2f(unsigned short s) {
    return __uint_as_float(((unsigned)s) << 16);
}
__device__ __forceinline__ unsigned pkbf(float a, float b) {   // v_cvt_pk_bf16_f32
    union { __hip_bfloat162 h; unsigned u; } c;
    c.h = __float22bfloat162_rn(make_float2(a, b));
    return c.u;
}

// bilinear setup: 4 clamped corner record offsets (in shorts) + 4 mask-folded weights
__device__ __forceinline__ void bl_setup(int h, int w, int r, int s, float oy, float ox,
                                         int* a, float* wg) {
    float sy = (float)(h + r) + oy;
    float sx = (float)(w + s) + ox;
    float fy = floorf(sy), fx = floorf(sx);
    int   y0 = (int)fy, x0 = (int)fx;
    int   y1 = y0 + 1, x1 = x0 + 1;
    float wy1 = sy - fy, wx1 = sx - fx;
    float wy0 = 1.f - wy1, wx0 = 1.f - wx1;
    float m00 = (y0 >= 0 && y0 < HH && x0 >= 0 && x0 < WW) ? 1.f : 0.f;
    float m01 = (y0 >= 0 && y0 < HH && x1 >= 0 && x1 < WW) ? 1.f : 0.f;
    float m10 = (y1 >= 0 && y1 < HH && x0 >= 0 && x0 < WW) ? 1.f : 0.f;
    float m11 = (y1 >= 0 && y1 < HH && x1 >= 0 && x1 < WW) ? 1.f : 0.f;
    int cy0 = min(max(y0, 0), HH - 1), cy1 = min(max(y1, 0), HH - 1);
    int cx0 = min(max(x0, 0), WW - 1), cx1 = min(max(x1, 0), WW - 1);
    a[0] = (cy0 * WW + cx0) * 64;  a[1] = (cy0 * WW + cx1) * 64;
    a[2] = (cy1 * WW + cx0) * 64;  a[3] = (cy1 * WW + cx1) * 64;
    wg[0] = wy0 * wx0 * m00;  wg[1] = wy0 * wx1 * m01;
    wg[2] = wy1 * wx0 * m10;  wg[3] = wy1 * wx1 * m11;
}

// ---------------------------------------------------------------------------
// Kernel 1: x NCHW fp32 -> xt NHWC bf16. Blocks < 216 build B-frag-ordered
// weights wTb2 [tap][ct][kc][qd][ln][ch] and owTb2 [tap][jt][kc][qd][ln][ch].
// (unchanged)
// ---------------------------------------------------------------------------
__global__ __launch_bounds__(256) void xcvt_prep(const float* __restrict__ x,
                                                 const float* __restrict__ weight,
                                                 const float* __restrict__ off_w,
                                                 unsigned short* __restrict__ xt,
                                                 unsigned short* __restrict__ wTb2,
                                                 unsigned short* __restrict__ owTb2) {
    __shared__ unsigned short T[64 * 64];   // [px][8 chunks], chunk' = chunk ^ (px&7)
    int bid   = blockIdx.x;                 // 1152
    int t     = threadIdx.x;
    int b     = bid & 7;                    // XCD-affine
    int pbase = (bid >> 3) * 64;
    int pl    = t & 63;
    int q     = t >> 6;                     // c-group 0..3 (chunks 2q, 2q+1)

    const float* xp = x + ((size_t)(b * 64 + q * 16)) * HW + pbase + pl;
    unsigned short hb[16];
#pragma unroll
    for (int i = 0; i < 16; ++i) hb[i] = f2bf_bits(xp[(size_t)i * HW]);

    uint4 w0, w1;
    w0.x = hb[0]  | (hb[1]  << 16); w0.y = hb[2]  | (hb[3]  << 16);
    w0.z = hb[4]  | (hb[5]  << 16); w0.w = hb[6]  | (hb[7]  << 16);
    w1.x = hb[8]  | (hb[9]  << 16); w1.y = hb[10] | (hb[11] << 16);
    w1.z = hb[12] | (hb[13] << 16); w1.w = hb[14] | (hb[15] << 16);
    int sw = pl & 7;
    *(uint4*)&T[pl * 64 + (((2 * q)     ^ sw) << 3)] = w0;
    *(uint4*)&T[pl * 64 + (((2 * q + 1) ^ sw) << 3)] = w1;
    __syncthreads();

    int row = t >> 2, rs = row & 7;
    uint4 a  = *(const uint4*)&T[row * 64 + ((((t & 3) * 2)     ^ rs) << 3)];
    uint4 b2 = *(const uint4*)&T[row * 64 + ((((t & 3) * 2 + 1) ^ rs) << 3)];
    unsigned short* dst = xt + ((size_t)(b * HW + pbase)) * 64 + t * 16;
    *(uint4*)dst       = a;
    *(uint4*)(dst + 8) = b2;

    if (bid < 216) {                        // 216*256 = 36864 + 18432
        int i = bid * 256 + t;
        if (i < 36864) {
            int ch = i & 7, lnn = (i >> 3) & 15, qdd = (i >> 7) & 3;
            int kc = (i >> 9) & 1, ct = (i >> 10) & 3, tap = i >> 12;
            int co = ct * 16 + lnn;
            int c  = kc * 32 + qdd * 8 + ch;
            wTb2[i] = f2bf_bits(weight[(co * 64 + c) * 9 + tap]);
        } else {
            int f = i - 36864;
            int ch = f & 7, lnn = (f >> 3) & 15, qdd = (f >> 7) & 3;
            int kc = (f >> 9) & 1, jt = (f >> 10) & 1, tap = f >> 11;
            int j = jt * 16 + lnn;
            int c = kc * 32 + qdd * 8 + ch;
            owTb2[f] = (j < 18) ? f2bf_bits(off_w[(j * 64 + c) * 9 + tap]) : (unsigned short)0;
        }
    }
}

// ---------------------------------------------------------------------------
// Kernel 2 (barrier-free + sched_barrier-enforced pipeline):
// R14 found the compiler SINKS prefetch loads to their uses (VGPR stayed 60),
// re-serializing every tap at full memory latency. sched_barrier(0) fences
// forbid that motion: phase A issues all 18 patch loads before any consume;
// phase B runs a depth-2 slot pipeline with a fence per iteration, so each
// tap's 8 corner loads stay in flight across a full iteration of compute.
// ---------------------------------------------------------------------------
__global__ __launch_bounds__(256, 2) void deform_all(const unsigned short* __restrict__ xt,
                                                     const unsigned short* __restrict__ wTb2,
                                                     const unsigned short* __restrict__ owTb2,
                                                     const float* __restrict__ bias,
                                                     const float* __restrict__ ob,
                                                     float* __restrict__ out) {
    __shared__ float offs[4][16 * 20];      // per-wave private [px][18 j + pad]

    int bid   = blockIdx.x;                 // 1152
    int t     = threadIdx.x;
    int b     = bid & 7;                    // image per XCD
    int wv    = t >> 6;
    int l     = t & 63;
    int ln    = l & 15;                     // pixel within the wave's 16-px tile
    int qd    = l >> 4;                     // k-chunk (8 channels)
    int pbase = (bid >> 3) * 64 + wv * 16;  // wave's pixel base
    int px    = pbase + ln;
    int h     = px / WW, w = px - h * WW;

    const unsigned short* xb = xt + (size_t)b * HW * 64;

    // ================= phase A: issue ALL 18 patch loads, then fence =========
    uint4 pa0[9], pa1[9];
    int   vmsk[9];
#pragma unroll
    for (int tap = 0; tap < 9; ++tap) {
        int  r  = tap / 3, s = tap - r * 3;
        int  iy = h - 1 + r, ix = w - 1 + s;
        vmsk[tap] = ((iy >= 0) & (iy < HH) & (ix >= 0) & (ix < WW)) ? -1 : 0;
        int  rec = (min(max(iy, 0), HH - 1) * WW + min(max(ix, 0), WW - 1)) * 64;
        pa0[tap] = *(const uint4*)(xb + rec + qd * 8);
        pa1[tap] = *(const uint4*)(xb + rec + 32 + qd * 8);
    }
    __builtin_amdgcn_sched_barrier(0);      // loads may NOT sink below this

    f32x4 aj0 = {0.f, 0.f, 0.f, 0.f};
    f32x4 aj1 = {0.f, 0.f, 0.f, 0.f};
#pragma unroll
    for (int tap = 0; tap < 9; ++tap) {
        unsigned m = (unsigned)vmsk[tap];
        BF8 a0, a1;
        a0.u.x = pa0[tap].x & m; a0.u.y = pa0[tap].y & m;
        a0.u.z = pa0[tap].z & m; a0.u.w = pa0[tap].w & m;
        a1.u.x = pa1[tap].x & m; a1.u.y = pa1[tap].y & m;
        a1.u.z = pa1[tap].z & m; a1.u.w = pa1[tap].w & m;

        const unsigned short* base0 = owTb2 + (size_t)tap * 2048 + l * 8;
        BF8 b00, b01, b10, b11;                            // [jt][kc]
        b00.u = *(const uint4*)(base0);
        b01.u = *(const uint4*)(base0 + 512);
        b10.u = *(const uint4*)(base0 + 1024);
        b11.u = *(const uint4*)(base0 + 1536);
        aj0 = __builtin_amdgcn_mfma_f32_16x16x32_bf16(a0.v, b00.v, aj0, 0, 0, 0);
        aj0 = __builtin_amdgcn_mfma_f32_16x16x32_bf16(a1.v, b01.v, aj0, 0, 0, 0);
        aj1 = __builtin_amdgcn_mfma_f32_16x16x32_bf16(a0.v, b10.v, aj1, 0, 0, 0);
        aj1 = __builtin_amdgcn_mfma_f32_16x16x32_bf16(a1.v, b11.v, aj1, 0, 0, 0);
    }

    // wave-local transpose (DS ops are wave-ordered: no barrier needed)
    {
        float* ow_ = offs[wv];
        float  obj = ob[ln];
#pragma unroll
        for (int rg = 0; rg < 4; ++rg) ow_[(qd * 4 + rg) * 20 + ln] = aj0[rg] + obj;
        if (ln < 2) {
            float obj1 = ob[16 + ln];
#pragma unroll
            for (int rg = 0; rg < 4; ++rg) ow_[(qd * 4 + rg) * 20 + 16 + ln] = aj1[rg] + obj1;
        }
    }
    float oy[9], ox[9];
#pragma unroll
    for (int k = 0; k < 9; ++k) {
        float2 p = *(const float2*)&offs[wv][ln * 20 + 2 * k];
        oy[k] = p.x; ox[k] = p.y;
    }

    // ================= phase B: fenced depth-2 pipeline ======================
    f32x4 acc[4] = {{0.f,0.f,0.f,0.f},{0.f,0.f,0.f,0.f},{0.f,0.f,0.f,0.f},{0.f,0.f,0.f,0.f}};

    uint4 cf0[2][4], cf1[2][4];     // [slot][corner] in-flight destinations
    float gs[2][4];                 // per-slot bilinear weights

    {   // prologue: issue taps 0 and 1
        int a_[4];
        bl_setup(h, w, 0, 0, oy[0], ox[0], a_, gs[0]);
#pragma unroll
        for (int c = 0; c < 4; ++c) {
            cf0[0][c] = *(const uint4*)(xb + a_[c] + qd * 8);
            cf1[0][c] = *(const uint4*)(xb + a_[c] + 32 + qd * 8);
        }
        bl_setup(h, w, 0, 1, oy[1], ox[1], a_, gs[1]);
#pragma unroll
        for (int c = 0; c < 4; ++c) {
            cf0[1][c] = *(const uint4*)(xb + a_[c] + qd * 8);
            cf1[1][c] = *(const uint4*)(xb + a_[c] + 32 + qd * 8);
        }
    }
    __builtin_amdgcn_sched_barrier(0);

#pragma unroll
    for (int k = 0; k < 9; ++k) {
        int slot = k & 1;

        // consume tap k (tap k+1's 8 loads remain outstanding: vmcnt(8)-style)
        BF8 A0, A1;
        {
            BF8 q0, q1, q2, q3, r0, r1, r2, r3;
            q0.u = cf0[slot][0]; q1.u = cf0[slot][1]; q2.u = cf0[slot][2]; q3.u = cf0[slot][3];
            r0.u = cf1[slot][0]; r1.u = cf1[slot][1]; r2.u = cf1[slot][2]; r3.u = cf1[slot][3];
            float g0 = gs[slot][0], g1 = gs[slot][1], g2 = gs[slot][2], g3 = gs[slot][3];
            float v0[8], v1[8];
#pragma unroll
            for (int i = 0; i < 8; ++i) {
                v0[i] = g0 * bf2f(q0.s[i]) + g1 * bf2f(q1.s[i])
                      + g2 * bf2f(q2.s[i]) + g3 * bf2f(q3.s[i]);
                v1[i] = g0 * bf2f(r0.s[i]) + g1 * bf2f(r1.s[i])
                      + g2 * bf2f(r2.s[i]) + g3 * bf2f(r3.s[i]);
            }
            A0.u.x = pkbf(v0[0], v0[1]); A0.u.y = pkbf(v0[2], v0[3]);
            A0.u.z = pkbf(v0[4], v0[5]); A0.u.w = pkbf(v0[6], v0[7]);
            A1.u.x = pkbf(v1[0], v1[1]); A1.u.y = pkbf(v1[2], v1[3]);
            A1.u.z = pkbf(v1[4], v1[5]); A1.u.w = pkbf(v1[6], v1[7]);
        }

        // refill this slot with tap k+2 (consumed next-next iteration)
        if (k + 2 < 9) {
            int kk = k + 2;
            int r = kk / 3, s = kk - r * 3;
            int a_[4];
            bl_setup(h, w, r, s, oy[kk], ox[kk], a_, gs[slot]);
#pragma unroll
            for (int c = 0; c < 4; ++c) {
                cf0[slot][c] = *(const uint4*)(xb + a_[c] + qd * 8);
                cf1[slot][c] = *(const uint4*)(xb + a_[c] + 32 + qd * 8);
            }
        }

        // MFMA: 4 co-tiles x 2 k-chunks; B-frags = contiguous 1 KB L1 bursts
        const unsigned short* wb = wTb2 + (size_t)k * 4096 + l * 8;
#pragma unroll
        for (int ct = 0; ct < 4; ++ct) {
            BF8 B0, B1;
            B0.u = *(const uint4*)(wb + ct * 1024);
            B1.u = *(const uint4*)(wb + ct * 1024 + 512);
            acc[ct] = __builtin_amdgcn_mfma_f32_16x16x32_bf16(A0.v, B0.v, acc[ct], 0, 0, 0);
            acc[ct] = __builtin_amdgcn_mfma_f32_16x16x32_bf16(A1.v, B1.v, acc[ct], 0, 0, 0);
        }

        __builtin_amdgcn_sched_barrier(0);  // pin iteration boundary: k+2's
                                            // loads stay issued before k+1's consume
    }

    // ---- epilogue: D col = co (ct*16+ln), rows px = qd*4+rg ----
#pragma unroll
    for (int ct = 0; ct < 4; ++ct) {
        int   co = ct * 16 + ln;
        float bv = bias[co];
        float4 st;
        st.x = acc[ct][0] + bv; st.y = acc[ct][1] + bv;
        st.z = acc[ct][2] + bv; st.w = acc[ct][3] + bv;
        *(float4*)(out + ((size_t)(b * 64 + co)) * HW + pbase + qd * 4) = st;
    }
}

// ---------------------------------------------------------------------------
extern "C" void kernel_launch(void* const* d_in, const int* in_sizes, int n_in,
                              void* d_out, int out_size, void* d_ws, size_t ws_size,
                              hipStream_t stream) {
    const float* x      = (const float*)d_in[0];   // 8*64*96*96
    const float* weight = (const float*)d_in[1];   // 64*64*3*3
    const float* bias   = (const float*)d_in[2];   // 64
    const float* off_w  = (const float*)d_in[3];   // 18*64*3*3
    const float* off_b  = (const float*)d_in[4];   // 18
    float* out = (float*)d_out;

    unsigned short* xt    = (unsigned short*)d_ws; // 4,718,592 bf16
    unsigned short* wTb2  = xt + 4718592;          // 36,864 bf16 (frag-ordered)
    unsigned short* owTb2 = wTb2 + 36864;          // 18,432 bf16 (frag-ordered)

    hipLaunchKernelGGL(xcvt_prep,  dim3(1152), dim3(256), 0, stream,
                       x, weight, off_w, xt, wTb2, owTb2);
    hipLaunchKernelGGL(deform_all, dim3(1152), dim3(256), 0, stream,
                       xt, wTb2, owTb2, bias, off_b, out);
}

// Round 16
// 140.164 us; speedup vs baseline: 1.0539x; 1.0539x over previous
//
#include <hip/hip_runtime.h>
#include <hip/hip_bf16.h>

#define HH 96
#define WW 96
#define HW 9216
#define NB 8

typedef __bf16 bf16x8 __attribute__((ext_vector_type(8)));
typedef float  f32x4  __attribute__((ext_vector_type(4)));

union BF8 { uint4 u; bf16x8 v; unsigned short s[8]; };

__device__ __forceinline__ unsigned short f2bf_bits(float f) {
    unsigned u = __float_as_uint(f);
    unsigned r = u + 0x7FFFu + ((u >> 16) & 1u);     // RNE
    return (unsigned short)(r >> 16);
}
__device__ __forceinline__ float bf2f(unsigned short s) {
    return __uint_as_float(((unsigned)s) << 16);
}
__device__ __forceinline__ unsigned pkbf(float a, float b) {   // v_cvt_pk_bf16_f32
    union { __hip_bfloat162 h; unsigned u; } c;
    c.h = __float22bfloat162_rn(make_float2(a, b));
    return c.u;
}

// bilinear setup: 4 clamped corner record offsets (in shorts) + 4 mask-folded weights
__device__ __forceinline__ void bl_setup(int h, int w, int r, int s, float oy, float ox,
                                         int* a, float* wg) {
    float sy = (float)(h + r) + oy;
    float sx = (float)(w + s) + ox;
    float fy = floorf(sy), fx = floorf(sx);
    int   y0 = (int)fy, x0 = (int)fx;
    int   y1 = y0 + 1, x1 = x0 + 1;
    float wy1 = sy - fy, wx1 = sx - fx;
    float wy0 = 1.f - wy1, wx0 = 1.f - wx1;
    float m00 = (y0 >= 0 && y0 < HH && x0 >= 0 && x0 < WW) ? 1.f : 0.f;
    float m01 = (y0 >= 0 && y0 < HH && x1 >= 0 && x1 < WW) ? 1.f : 0.f;
    float m10 = (y1 >= 0 && y1 < HH && x0 >= 0 && x0 < WW) ? 1.f : 0.f;
    float m11 = (y1 >= 0 && y1 < HH && x1 >= 0 && x1 < WW) ? 1.f : 0.f;
    int cy0 = min(max(y0, 0), HH - 1), cy1 = min(max(y1, 0), HH - 1);
    int cx0 = min(max(x0, 0), WW - 1), cx1 = min(max(x1, 0), WW - 1);
    a[0] = (cy0 * WW + cx0) * 64;  a[1] = (cy0 * WW + cx1) * 64;
    a[2] = (cy1 * WW + cx0) * 64;  a[3] = (cy1 * WW + cx1) * 64;
    wg[0] = wy0 * wx0 * m00;  wg[1] = wy0 * wx1 * m01;
    wg[2] = wy1 * wx0 * m10;  wg[3] = wy1 * wx1 * m11;
}

// ---------------------------------------------------------------------------
// Kernel 1: x NCHW fp32 -> xt NHWC bf16. Blocks < 216 build B-frag-ordered
// weights wTb2 [tap][ct][kc][qd][ln][ch] and owTb2 [tap][jt][kc][qd][ln][ch].
// (unchanged)
// ---------------------------------------------------------------------------
__global__ __launch_bounds__(256) void xcvt_prep(const float* __restrict__ x,
                                                 const float* __restrict__ weight,
                                                 const float* __restrict__ off_w,
                                                 unsigned short* __restrict__ xt,
                                                 unsigned short* __restrict__ wTb2,
                                                 unsigned short* __restrict__ owTb2) {
    __shared__ unsigned short T[64 * 64];   // [px][8 chunks], chunk' = chunk ^ (px&7)
    int bid   = blockIdx.x;                 // 1152
    int t     = threadIdx.x;
    int b     = bid & 7;                    // XCD-affine
    int pbase = (bid >> 3) * 64;
    int pl    = t & 63;
    int q     = t >> 6;                     // c-group 0..3 (chunks 2q, 2q+1)

    const float* xp = x + ((size_t)(b * 64 + q * 16)) * HW + pbase + pl;
    unsigned short hb[16];
#pragma unroll
    for (int i = 0; i < 16; ++i) hb[i] = f2bf_bits(xp[(size_t)i * HW]);

    uint4 w0, w1;
    w0.x = hb[0]  | (hb[1]  << 16); w0.y = hb[2]  | (hb[3]  << 16);
    w0.z = hb[4]  | (hb[5]  << 16); w0.w = hb[6]  | (hb[7]  << 16);
    w1.x = hb[8]  | (hb[9]  << 16); w1.y = hb[10] | (hb[11] << 16);
    w1.z = hb[12] | (hb[13] << 16); w1.w = hb[14] | (hb[15] << 16);
    int sw = pl & 7;
    *(uint4*)&T[pl * 64 + (((2 * q)     ^ sw) << 3)] = w0;
    *(uint4*)&T[pl * 64 + (((2 * q + 1) ^ sw) << 3)] = w1;
    __syncthreads();

    int row = t >> 2, rs = row & 7;
    uint4 a  = *(const uint4*)&T[row * 64 + ((((t & 3) * 2)     ^ rs) << 3)];
    uint4 b2 = *(const uint4*)&T[row * 64 + ((((t & 3) * 2 + 1) ^ rs) << 3)];
    unsigned short* dst = xt + ((size_t)(b * HW + pbase)) * 64 + t * 16;
    *(uint4*)dst       = a;
    *(uint4*)(dst + 8) = b2;

    if (bid < 216) {                        // 216*256 = 36864 + 18432
        int i = bid * 256 + t;
        if (i < 36864) {
            int ch = i & 7, lnn = (i >> 3) & 15, qdd = (i >> 7) & 3;
            int kc = (i >> 9) & 1, ct = (i >> 10) & 3, tap = i >> 12;
            int co = ct * 16 + lnn;
            int c  = kc * 32 + qdd * 8 + ch;
            wTb2[i] = f2bf_bits(weight[(co * 64 + c) * 9 + tap]);
        } else {
            int f = i - 36864;
            int ch = f & 7, lnn = (f >> 3) & 15, qdd = (f >> 7) & 3;
            int kc = (f >> 9) & 1, jt = (f >> 10) & 1, tap = f >> 11;
            int j = jt * 16 + lnn;
            int c = kc * 32 + qdd * 8 + ch;
            owTb2[f] = (j < 18) ? f2bf_bits(off_w[(j * 64 + c) * 9 + tap]) : (unsigned short)0;
        }
    }
}

// ---------------------------------------------------------------------------
// Kernel 2: R15 structure + the vmcnt fix. wTb2 lives in LDS (staged once,
// barrier BEFORE any prefetch is in flight), so phase B's global stream is
// corners-only: consuming tap k waits vmcnt(8/16), never vmcnt(0) — the
// prefetch finally survives the wait. B-frags come via ds_read (lgkmcnt,
// independent counter). Phase A: all patch loads up front + depth-2 owTb2
// rotation. sched_barrier(0) pins the issue order.
// ---------------------------------------------------------------------------
__global__ __launch_bounds__(256, 2) void deform_all(const unsigned short* __restrict__ xt,
                                                     const unsigned short* __restrict__ wTb2,
                                                     const unsigned short* __restrict__ owTb2,
                                                     const float* __restrict__ bias,
                                                     const float* __restrict__ ob,
                                                     float* __restrict__ out) {
    __shared__ unsigned short Wlds[36864];  // 72 KB: wTb2 staged
    __shared__ float offs[4][16 * 20];      // per-wave private [px][18 j + pad]

    int bid   = blockIdx.x;                 // 1152
    int t     = threadIdx.x;
    int b     = bid & 7;                    // image per XCD
    int wv    = t >> 6;
    int l     = t & 63;
    int ln    = l & 15;                     // pixel within the wave's 16-px tile
    int qd    = l >> 4;                     // k-chunk (8 channels)
    int pbase = (bid >> 3) * 64 + wv * 16;  // wave's pixel base
    int px    = pbase + ln;
    int h     = px / WW, w = px - h * WW;

    const unsigned short* xb = xt + (size_t)b * HW * 64;

    // ---- stage wTb2 -> LDS (coalesced; the ONLY block barrier, placed
    //      before any global prefetch is outstanding) ----
    {
        const uint4* src = (const uint4*)wTb2;
        uint4*       dst = (uint4*)Wlds;
#pragma unroll
        for (int i = 0; i < 18; ++i) dst[i * 256 + t] = src[i * 256 + t];
    }
    __syncthreads();

    // ================= phase A: all 18 patch loads up front =================
    uint4 pa0[9], pa1[9];
    int   vmsk[9];
#pragma unroll
    for (int tap = 0; tap < 9; ++tap) {
        int  r  = tap / 3, s = tap - r * 3;
        int  iy = h - 1 + r, ix = w - 1 + s;
        vmsk[tap] = ((iy >= 0) & (iy < HH) & (ix >= 0) & (ix < WW)) ? -1 : 0;
        int  rec = (min(max(iy, 0), HH - 1) * WW + min(max(ix, 0), WW - 1)) * 64;
        pa0[tap] = *(const uint4*)(xb + rec + qd * 8);
        pa1[tap] = *(const uint4*)(xb + rec + 32 + qd * 8);
    }
    // depth-2 rotation of owTb2 B-loads (global stream = patch + these only)
    uint4 obf[2][4];
#pragma unroll
    for (int p = 0; p < 2; ++p) {
        const unsigned short* base0 = owTb2 + (size_t)p * 2048 + l * 8;
        obf[p][0] = *(const uint4*)(base0);
        obf[p][1] = *(const uint4*)(base0 + 512);
        obf[p][2] = *(const uint4*)(base0 + 1024);
        obf[p][3] = *(const uint4*)(base0 + 1536);
    }
    __builtin_amdgcn_sched_barrier(0);

    f32x4 aj0 = {0.f, 0.f, 0.f, 0.f};
    f32x4 aj1 = {0.f, 0.f, 0.f, 0.f};
#pragma unroll
    for (int tap = 0; tap < 9; ++tap) {
        int slot = tap & 1;
        unsigned m = (unsigned)vmsk[tap];
        BF8 a0, a1, b00, b01, b10, b11;
        a0.u.x = pa0[tap].x & m; a0.u.y = pa0[tap].y & m;
        a0.u.z = pa0[tap].z & m; a0.u.w = pa0[tap].w & m;
        a1.u.x = pa1[tap].x & m; a1.u.y = pa1[tap].y & m;
        a1.u.z = pa1[tap].z & m; a1.u.w = pa1[tap].w & m;
        b00.u = obf[slot][0]; b01.u = obf[slot][1];
        b10.u = obf[slot][2]; b11.u = obf[slot][3];

        if (tap + 2 < 9) {      // refill slot (consumed 2 iterations later)
            const unsigned short* base0 = owTb2 + (size_t)(tap + 2) * 2048 + l * 8;
            obf[slot][0] = *(const uint4*)(base0);
            obf[slot][1] = *(const uint4*)(base0 + 512);
            obf[slot][2] = *(const uint4*)(base0 + 1024);
            obf[slot][3] = *(const uint4*)(base0 + 1536);
        }

        aj0 = __builtin_amdgcn_mfma_f32_16x16x32_bf16(a0.v, b00.v, aj0, 0, 0, 0);
        aj0 = __builtin_amdgcn_mfma_f32_16x16x32_bf16(a1.v, b01.v, aj0, 0, 0, 0);
        aj1 = __builtin_amdgcn_mfma_f32_16x16x32_bf16(a0.v, b10.v, aj1, 0, 0, 0);
        aj1 = __builtin_amdgcn_mfma_f32_16x16x32_bf16(a1.v, b11.v, aj1, 0, 0, 0);
        __builtin_amdgcn_sched_barrier(0);
    }

    // wave-local transpose (DS ops are wave-ordered: no barrier needed)
    {
        float* ow_ = offs[wv];
        float  obj = ob[ln];
#pragma unroll
        for (int rg = 0; rg < 4; ++rg) ow_[(qd * 4 + rg) * 20 + ln] = aj0[rg] + obj;
        if (ln < 2) {
            float obj1 = ob[16 + ln];
#pragma unroll
            for (int rg = 0; rg < 4; ++rg) ow_[(qd * 4 + rg) * 20 + 16 + ln] = aj1[rg] + obj1;
        }
    }
    float oy[9], ox[9];
#pragma unroll
    for (int k = 0; k < 9; ++k) {
        float2 p = *(const float2*)&offs[wv][ln * 20 + 2 * k];
        oy[k] = p.x; ox[k] = p.y;
    }

    // ================= phase B: corners-only vmcnt stream, B from LDS ========
    f32x4 acc[4] = {{0.f,0.f,0.f,0.f},{0.f,0.f,0.f,0.f},{0.f,0.f,0.f,0.f},{0.f,0.f,0.f,0.f}};

    uint4 cf0[2][4], cf1[2][4];     // [slot][corner] in-flight destinations
    float gs[2][4];                 // per-slot bilinear weights

    {   // prologue: issue taps 0 and 1
        int a_[4];
        bl_setup(h, w, 0, 0, oy[0], ox[0], a_, gs[0]);
#pragma unroll
        for (int c = 0; c < 4; ++c) {
            cf0[0][c] = *(const uint4*)(xb + a_[c] + qd * 8);
            cf1[0][c] = *(const uint4*)(xb + a_[c] + 32 + qd * 8);
        }
        bl_setup(h, w, 0, 1, oy[1], ox[1], a_, gs[1]);
#pragma unroll
        for (int c = 0; c < 4; ++c) {
            cf0[1][c] = *(const uint4*)(xb + a_[c] + qd * 8);
            cf1[1][c] = *(const uint4*)(xb + a_[c] + 32 + qd * 8);
        }
    }
    __builtin_amdgcn_sched_barrier(0);

#pragma unroll
    for (int k = 0; k < 9; ++k) {
        int slot = k & 1;

        // B-frags from LDS (lgkmcnt — does not disturb the vmcnt pipeline)
        BF8 B0[4], B1[4];
#pragma unroll
        for (int ct = 0; ct < 4; ++ct) {
            B0[ct].u = *(const uint4*)&Wlds[k * 4096 + ct * 1024 + l * 8];
            B1[ct].u = *(const uint4*)&Wlds[k * 4096 + ct * 1024 + 512 + l * 8];
        }

        // consume tap k's corners (waits vmcnt(8): only tap k+1 outstanding)
        BF8 A0, A1;
        {
            BF8 q0, q1, q2, q3, r0, r1, r2, r3;
            q0.u = cf0[slot][0]; q1.u = cf0[slot][1]; q2.u = cf0[slot][2]; q3.u = cf0[slot][3];
            r0.u = cf1[slot][0]; r1.u = cf1[slot][1]; r2.u = cf1[slot][2]; r3.u = cf1[slot][3];
            float g0 = gs[slot][0], g1 = gs[slot][1], g2 = gs[slot][2], g3 = gs[slot][3];
            float v0[8], v1[8];
#pragma unroll
            for (int i = 0; i < 8; ++i) {
                v0[i] = g0 * bf2f(q0.s[i]) + g1 * bf2f(q1.s[i])
                      + g2 * bf2f(q2.s[i]) + g3 * bf2f(q3.s[i]);
                v1[i] = g0 * bf2f(r0.s[i]) + g1 * bf2f(r1.s[i])
                      + g2 * bf2f(r2.s[i]) + g3 * bf2f(r3.s[i]);
            }
            A0.u.x = pkbf(v0[0], v0[1]); A0.u.y = pkbf(v0[2], v0[3]);
            A0.u.z = pkbf(v0[4], v0[5]); A0.u.w = pkbf(v0[6], v0[7]);
            A1.u.x = pkbf(v1[0], v1[1]); A1.u.y = pkbf(v1[2], v1[3]);
            A1.u.z = pkbf(v1[4], v1[5]); A1.u.w = pkbf(v1[6], v1[7]);
        }

        // refill this slot with tap k+2 (consumed 2 iterations later)
        if (k + 2 < 9) {
            int kk = k + 2;
            int r = kk / 3, s = kk - r * 3;
            int a_[4];
            bl_setup(h, w, r, s, oy[kk], ox[kk], a_, gs[slot]);
#pragma unroll
            for (int c = 0; c < 4; ++c) {
                cf0[slot][c] = *(const uint4*)(xb + a_[c] + qd * 8);
                cf1[slot][c] = *(const uint4*)(xb + a_[c] + 32 + qd * 8);
            }
        }

        // MFMA: 4 co-tiles x 2 k-chunks
#pragma unroll
        for (int ct = 0; ct < 4; ++ct) {
            acc[ct] = __builtin_amdgcn_mfma_f32_16x16x32_bf16(A0.v, B0[ct].v, acc[ct], 0, 0, 0);
            acc[ct] = __builtin_amdgcn_mfma_f32_16x16x32_bf16(A1.v, B1[ct].v, acc[ct], 0, 0, 0);
        }

        __builtin_amdgcn_sched_barrier(0);  // pin iteration boundary
    }

    // ---- epilogue: D col = co (ct*16+ln), rows px = qd*4+rg ----
#pragma unroll
    for (int ct = 0; ct < 4; ++ct) {
        int   co = ct * 16 + ln;
        float bv = bias[co];
        float4 st;
        st.x = acc[ct][0] + bv; st.y = acc[ct][1] + bv;
        st.z = acc[ct][2] + bv; st.w = acc[ct][3] + bv;
        *(float4*)(out + ((size_t)(b * 64 + co)) * HW + pbase + qd * 4) = st;
    }
}

// ---------------------------------------------------------------------------
extern "C" void kernel_launch(void* const* d_in, const int* in_sizes, int n_in,
                              void* d_out, int out_size, void* d_ws, size_t ws_size,
                              hipStream_t stream) {
    const float* x      = (const float*)d_in[0];   // 8*64*96*96
    const float* weight = (const float*)d_in[1];   // 64*64*3*3
    const float* bias   = (const float*)d_in[2];   // 64
    const float* off_w  = (const float*)d_in[3];   // 18*64*3*3
    const float* off_b  = (const float*)d_in[4];   // 18
    float* out = (float*)d_out;

    unsigned short* xt    = (unsigned short*)d_ws; // 4,718,592 bf16
    unsigned short* wTb2  = xt + 4718592;          // 36,864 bf16 (frag-ordered)
    unsigned short* owTb2 = wTb2 + 36864;          // 18,432 bf16 (frag-ordered)

    hipLaunchKernelGGL(xcvt_prep,  dim3(1152), dim3(256), 0, stream,
                       x, weight, off_w, xt, wTb2, owTb2);
    hipLaunchKernelGGL(deform_all, dim3(1152), dim3(256), 0, stream,
                       xt, wTb2, owTb2, bias, off_b, out);
}

// Round 17
// 131.530 us; speedup vs baseline: 1.1231x; 1.0656x over previous
//
#include <hip/hip_runtime.h>
#include <hip/hip_bf16.h>

#define HH 96
#define WW 96
#define HW 9216
#define NB 8

typedef __bf16 bf16x8 __attribute__((ext_vector_type(8)));
typedef float  f32x4  __attribute__((ext_vector_type(4)));

union BF8 { uint4 u; bf16x8 v; unsigned short s[8]; };

__device__ __forceinline__ unsigned short f2bf_bits(float f) {
    unsigned u = __float_as_uint(f);
    unsigned r = u + 0x7FFFu + ((u >> 16) & 1u);     // RNE
    return (unsigned short)(r >> 16);
}
__device__ __forceinline__ float bf2f(unsigned short s) {
    return __uint_as_float(((unsigned)s) << 16);
}
__device__ __forceinline__ unsigned pkbf(float a, float b) {   // v_cvt_pk_bf16_f32
    union { __hip_bfloat162 h; unsigned u; } c;
    c.h = __float22bfloat162_rn(make_float2(a, b));
    return c.u;
}

// bilinear setup: 4 clamped corner base offsets (in shorts) + 4 mask-folded weights
__device__ __forceinline__ void bl_setup(int h, int w, int r, int s, float oy, float ox,
                                         int* a, float* wg) {
    float sy = (float)(h + r) + oy;
    float sx = (float)(w + s) + ox;
    float fy = floorf(sy), fx = floorf(sx);
    int   y0 = (int)fy, x0 = (int)fx;
    int   y1 = y0 + 1, x1 = x0 + 1;
    float wy1 = sy - fy, wx1 = sx - fx;
    float wy0 = 1.f - wy1, wx0 = 1.f - wx1;
    float m00 = (y0 >= 0 && y0 < HH && x0 >= 0 && x0 < WW) ? 1.f : 0.f;
    float m01 = (y0 >= 0 && y0 < HH && x1 >= 0 && x1 < WW) ? 1.f : 0.f;
    float m10 = (y1 >= 0 && y1 < HH && x0 >= 0 && x0 < WW) ? 1.f : 0.f;
    float m11 = (y1 >= 0 && y1 < HH && x1 >= 0 && x1 < WW) ? 1.f : 0.f;
    int cy0 = min(max(y0, 0), HH - 1), cy1 = min(max(y1, 0), HH - 1);
    int cx0 = min(max(x0, 0), WW - 1), cx1 = min(max(x1, 0), WW - 1);
    a[0] = (cy0 * WW + cx0) * 64;  a[1] = (cy0 * WW + cx1) * 64;
    a[2] = (cy1 * WW + cx0) * 64;  a[3] = (cy1 * WW + cx1) * 64;
    wg[0] = wy0 * wx0 * m00;  wg[1] = wy0 * wx1 * m01;
    wg[2] = wy1 * wx0 * m10;  wg[3] = wy1 * wx1 * m11;
}

// ---------------------------------------------------------------------------
// Kernel 1: x NCHW fp32 -> xt NHWC bf16 (LDS transpose, XOR-swizzled).
// Blocks < 216 also build wTb [tap][co][c] and owTb [j(32)][tap*64+c].
// ---------------------------------------------------------------------------
__global__ __launch_bounds__(256) void xcvt_prep(const float* __restrict__ x,
                                                 const float* __restrict__ weight,
                                                 const float* __restrict__ off_w,
                                                 unsigned short* __restrict__ xt,
                                                 unsigned short* __restrict__ wTb,
                                                 unsigned short* __restrict__ owTb) {
    __shared__ unsigned short T[64 * 64];   // [px][8 chunks], chunk' = chunk ^ (px&7)
    int bid   = blockIdx.x;                 // 1152
    int t     = threadIdx.x;
    int b     = bid & 7;                    // XCD-affine
    int pbase = (bid >> 3) * 64;
    int pl    = t & 63;
    int q     = t >> 6;                     // c-group 0..3 (chunks 2q, 2q+1)

    const float* xp = x + ((size_t)(b * 64 + q * 16)) * HW + pbase + pl;
    unsigned short hb[16];
#pragma unroll
    for (int i = 0; i < 16; ++i) hb[i] = f2bf_bits(xp[(size_t)i * HW]);

    uint4 w0, w1;
    w0.x = hb[0]  | (hb[1]  << 16); w0.y = hb[2]  | (hb[3]  << 16);
    w0.z = hb[4]  | (hb[5]  << 16); w0.w = hb[6]  | (hb[7]  << 16);
    w1.x = hb[8]  | (hb[9]  << 16); w1.y = hb[10] | (hb[11] << 16);
    w1.z = hb[12] | (hb[13] << 16); w1.w = hb[14] | (hb[15] << 16);
    int sw = pl & 7;
    *(uint4*)&T[pl * 64 + (((2 * q)     ^ sw) << 3)] = w0;
    *(uint4*)&T[pl * 64 + (((2 * q + 1) ^ sw) << 3)] = w1;
    __syncthreads();

    int row = t >> 2, rs = row & 7;
    uint4 a  = *(const uint4*)&T[row * 64 + ((((t & 3) * 2)     ^ rs) << 3)];
    uint4 b2 = *(const uint4*)&T[row * 64 + ((((t & 3) * 2 + 1) ^ rs) << 3)];
    unsigned short* dst = xt + ((size_t)(b * HW + pbase)) * 64 + t * 16;
    *(uint4*)dst       = a;
    *(uint4*)(dst + 8) = b2;

    if (bid < 216) {                        // 216*256 = 36864 + 18432
        int i = bid * 256 + t;
        if (i < 36864) {
            int tap = i >> 12;
            int co  = (i >> 6) & 63;
            int c   = i & 63;
            wTb[i] = f2bf_bits(weight[(co * 64 + c) * 9 + tap]);
        } else {
            int f   = i - 36864;
            int j   = f / 576;
            int kk  = f - j * 576;
            int tap = kk >> 6;
            int c   = kk & 63;
            owTb[f] = (j < 18) ? f2bf_bits(off_w[(j * 64 + c) * 9 + tap]) : (unsigned short)0;
        }
    }
}

// ---------------------------------------------------------------------------
// Kernel 2 (fused): 32-px row-aligned tiles, 2304 blocks. (R12 best config)
// Phase A: zero-padded 3x34 halo in LDS (1 load pass + 1 barrier), then all
//          9 taps' A-frags are direct swizzled ds_reads -> MFMA vs owTb (L1).
// Phase B: 2 taps per barrier (paired double-buffer, 5 barriers) with
//          cross-step register prefetch of the next pair's 8 corner loads.
// ---------------------------------------------------------------------------
__global__ __launch_bounds__(256, 3) void deform_all(const unsigned short* __restrict__ xt,
                                                     const unsigned short* __restrict__ wTb,
                                                     const unsigned short* __restrict__ owTb,
                                                     const float* __restrict__ bias,
                                                     const float* __restrict__ ob,
                                                     float* __restrict__ out) {
    __shared__ unsigned short SH[2 * 2 * 32 * 64];   // 16 KB: halo (13 KB) / S pairs
    __shared__ float offs[32 * 20];                  // [px][18 j + pad]

    int bid   = blockIdx.x;                 // 2304 = 8 images x 288 tiles
    int t     = threadIdx.x;
    int b     = bid & 7;                    // image per XCD
    int pbase = (bid >> 3) * 32;            // row-aligned 32-px tile
    int r0    = pbase / WW;                 // whole tile shares this row
    int c0    = pbase - r0 * WW;            // 0, 32, or 64

    // staging role: thread = (pixel, chunk)
    int e   = t & 7;
    int pxl = t >> 3;                       // 0..31
    int h   = r0, w = c0 + pxl;
    int sw  = pxl & 7;

    // MFMA roles
    int ln = t & 15;
    int qd = (t >> 4) & 3;
    int wv = t >> 6;

    const unsigned short* xb = xt + (size_t)b * HW * 64;

    // ================= phase A: halo load (3 rows x 34 cols, zero-padded) =====
#pragma unroll
    for (int p = 0; p < 4; ++p) {
        int rec = p * 32 + pxl;
        if (rec < 102) {
            int hr = rec / 34, hc = rec - hr * 34;
            int gr = r0 - 1 + hr, gc = c0 - 1 + hc;
            bool vd = (gr >= 0) & (gr < HH) & (gc >= 0) & (gc < WW);
            uint4 v = make_uint4(0u, 0u, 0u, 0u);
            if (vd) v = *(const uint4*)(xb + (size_t)(gr * WW + gc) * 64 + e * 8);
            *(uint4*)&SH[rec * 64 + ((e ^ (hc & 7)) << 3)] = v;
        }
    }
    __syncthreads();

    // ---- phase A MFMA: 9 taps straight from halo LDS, no more barriers ----
    int ptA = wv & 1, jtA = wv >> 1;
    f32x4 accj = {0.f, 0.f, 0.f, 0.f};
#pragma unroll
    for (int tap = 0; tap < 9; ++tap) {
        int r = tap / 3, s = tap - r * 3;
        int cH = ptA * 16 + ln + s;                  // halo column for this lane
        int ba = (r * 34 + cH) * 64;
        BF8 fa0, fa1, fb0, fb1;
        fa0.u = *(const uint4*)&SH[ba + ((qd       ^ (cH & 7)) << 3)];
        fa1.u = *(const uint4*)&SH[ba + (((qd + 4) ^ (cH & 7)) << 3)];
        const unsigned short* brow = owTb + (size_t)(jtA * 16 + ln) * 576 + tap * 64 + qd * 8;
        fb0.u = *(const uint4*)brow;
        fb1.u = *(const uint4*)(brow + 32);
        accj = __builtin_amdgcn_mfma_f32_16x16x32_bf16(fa0.v, fb0.v, accj, 0, 0, 0);
        accj = __builtin_amdgcn_mfma_f32_16x16x32_bf16(fa1.v, fb1.v, accj, 0, 0, 0);
    }
    {
        int j = jtA * 16 + ln;
        if (j < 18) {
            int   rowp = ptA * 16 + qd * 4;
            float obj  = ob[j];
#pragma unroll
            for (int rg = 0; rg < 4; ++rg) offs[(rowp + rg) * 20 + j] = accj[rg] + obj;
        }
    }
    __syncthreads();   // offs visible; all halo reads done before S overwrites SH

    float oy[9], ox[9];
#pragma unroll
    for (int k = 0; k < 9; ++k) {
        float2 p = *(const float2*)&offs[pxl * 20 + 2 * k];
        oy[k] = p.x; ox[k] = p.y;
    }

    // ================= phase B: 2 taps per barrier + cross-step prefetch ======
    f32x4 acc[2] = {{0.f,0.f,0.f,0.f},{0.f,0.f,0.f,0.f}};

    uint4 cc[2][4], cn[2][4];
    float gc[2][4], gn[2][4];

    auto issue = [&](int tap, uint4 (&C)[4], float (&G)[4]) {
        int r = tap / 3, s = tap - r * 3;
        int aa[4];
        bl_setup(h, w, r, s, oy[tap], ox[tap], aa, G);
#pragma unroll
        for (int c = 0; c < 4; ++c) C[c] = *(const uint4*)(xb + aa[c] + e * 8);
    };

    issue(0, cc[0], gc[0]);
    issue(1, cc[1], gc[1]);

#pragma unroll
    for (int step = 0; step < 5; ++step) {
        int  buf  = step & 1;
        int  t0   = 2 * step;
        bool has1 = (t0 + 1) < 9;

        // prefetch next pair (loads fly across combine + barrier + MFMA)
        if (t0 + 2 < 9) issue(t0 + 2, cn[0], gn[0]);
        if (t0 + 3 < 9) issue(t0 + 3, cn[1], gn[1]);

        // combine current pair -> S slots
#pragma unroll
        for (int tp = 0; tp < 2; ++tp) {
            if (tp == 0 || has1) {
                BF8 q0, q1, q2, q3;
                q0.u = cc[tp][0]; q1.u = cc[tp][1]; q2.u = cc[tp][2]; q3.u = cc[tp][3];
                float vv[8];
#pragma unroll
                for (int i = 0; i < 8; ++i)
                    vv[i] = gc[tp][0] * bf2f(q0.s[i]) + gc[tp][1] * bf2f(q1.s[i])
                          + gc[tp][2] * bf2f(q2.s[i]) + gc[tp][3] * bf2f(q3.s[i]);
                uint4 sv;
                sv.x = pkbf(vv[0], vv[1]); sv.y = pkbf(vv[2], vv[3]);
                sv.z = pkbf(vv[4], vv[5]); sv.w = pkbf(vv[6], vv[7]);
                *(uint4*)&SH[((buf * 2 + tp) * 32 + pxl) * 64 + ((e ^ sw) << 3)] = sv;
            }
        }
        __syncthreads();

        // MFMA both taps; B-frags direct from L1-hot wTb
#pragma unroll
        for (int tp = 0; tp < 2; ++tp) {
            if (tp == 0 || has1) {
                int tk = t0 + tp;
                const unsigned short* wb = wTb + (size_t)tk * 4096 + (wv * 16 + ln) * 64 + qd * 8;
                BF8 fb0, fb1;
                fb0.u = *(const uint4*)wb;
                fb1.u = *(const uint4*)(wb + 32);
#pragma unroll
                for (int pt = 0; pt < 2; ++pt) {
                    int row = pt * 16 + ln, rs2 = row & 7;
                    BF8 fa0, fa1;
                    fa0.u = *(const uint4*)&SH[((buf * 2 + tp) * 32 + row) * 64 + ((qd       ^ rs2) << 3)];
                    fa1.u = *(const uint4*)&SH[((buf * 2 + tp) * 32 + row) * 64 + (((qd + 4) ^ rs2) << 3)];
                    acc[pt] = __builtin_amdgcn_mfma_f32_16x16x32_bf16(fa0.v, fb0.v, acc[pt], 0, 0, 0);
                    acc[pt] = __builtin_amdgcn_mfma_f32_16x16x32_bf16(fa1.v, fb1.v, acc[pt], 0, 0, 0);
                }
            }
        }
        // rotate pipeline
#pragma unroll
        for (int tp = 0; tp < 2; ++tp)
#pragma unroll
            for (int c = 0; c < 4; ++c) { cc[tp][c] = cn[tp][c]; gc[tp][c] = gn[tp][c]; }
    }

    // ---- epilogue: D col=co, rows px = pt*16 + qd*4 + rg ----
    int   co = wv * 16 + ln;
    float bv = bias[co];
    float* ob2 = out + ((size_t)(b * 64 + co)) * HW + pbase + qd * 4;
#pragma unroll
    for (int pt = 0; pt < 2; ++pt) {
        float4 st;
        st.x = acc[pt].x + bv; st.y = acc[pt].y + bv;
        st.z = acc[pt].z + bv; st.w = acc[pt].w + bv;
        *(float4*)(ob2 + pt * 16) = st;
    }
}

// ---------------------------------------------------------------------------
extern "C" void kernel_launch(void* const* d_in, const int* in_sizes, int n_in,
                              void* d_out, int out_size, void* d_ws, size_t ws_size,
                              hipStream_t stream) {
    const float* x      = (const float*)d_in[0];   // 8*64*96*96
    const float* weight = (const float*)d_in[1];   // 64*64*3*3
    const float* bias   = (const float*)d_in[2];   // 64
    const float* off_w  = (const float*)d_in[3];   // 18*64*3*3
    const float* off_b  = (const float*)d_in[4];   // 18
    float* out = (float*)d_out;

    unsigned short* xt   = (unsigned short*)d_ws;  // 4,718,592 bf16
    unsigned short* wTb  = xt + 4718592;           // 36,864 bf16
    unsigned short* owTb = wTb + 36864;            // 18,432 bf16

    hipLaunchKernelGGL(xcvt_prep,  dim3(1152), dim3(256), 0, stream,
                       x, weight, off_w, xt, wTb, owTb);
    hipLaunchKernelGGL(deform_all, dim3(2304), dim3(256), 0, stream,
                       xt, wTb, owTb, bias, off_b, out);
}